// Round 4
// baseline (100.442 us; speedup 1.0000x reference)
//
#include <hip/hip_runtime.h>
#include <hip/hip_bf16.h>
#include <math.h>

// Problem constants
#define BB   2
#define LL   2048
#define DD   512
#define KK   32
#define BL   (BB*LL)      // 4096
#define NCH  64           // chunks along L
#define LC   32           // rows per chunk

typedef unsigned short ushort_t;
typedef __bf16 bf16x8 __attribute__((ext_vector_type(8)));
typedef float  f32x4  __attribute__((ext_vector_type(4)));
typedef unsigned short ushort8 __attribute__((ext_vector_type(8)));

__device__ __forceinline__ void gl_lds16(const void* g, void* l) {
    __builtin_amdgcn_global_load_lds(
        (const __attribute__((address_space(1))) void*)g,
        (__attribute__((address_space(3))) void*)l, 16, 0, 0);
}
__device__ __forceinline__ ushort_t f2b(float f) {
    __bf16 b = (__bf16)f; return *(ushort_t*)&b;
}
__device__ __forceinline__ float b2f(ushort_t u) {
    unsigned int x = ((unsigned int)u) << 16; return *(float*)&x;
}

// ---------------------------------------------------------------------------
// prep: z=0: W1^T->Wct[0:512]; z=1: Wv^T->Wct[512:]; z=2: (g.Wo)^T->Wot;
//       z=3: cast x->xb; z=4 (2 blocks): u[n]=sum g[k]Wo[k][n], vb[n]=lnb@Wo+bo
// ---------------------------------------------------------------------------
__global__ __launch_bounds__(256) void prep(const float* __restrict__ W1,
                                            const float* __restrict__ Wv,
                                            const float* __restrict__ Wo,
                                            const float* __restrict__ x,
                                            const float* __restrict__ lng,
                                            const float* __restrict__ lnb,
                                            const float* __restrict__ bo,
                                            __hip_bfloat16* __restrict__ Wct,
                                            __hip_bfloat16* __restrict__ Wot,
                                            __hip_bfloat16* __restrict__ xb,
                                            float* __restrict__ U,
                                            float* __restrict__ VBc)
{
    __shared__ float tile[32][33];
    const int bz = blockIdx.z;
    const int tx = threadIdx.x, ty = threadIdx.y;
    const int t = ty * 32 + tx;

    if (bz == 3) {                      // cast x (2M floats): 256 blocks
        const int bid = blockIdx.y * 16 + blockIdx.x;
        const float4* src = (const float4*)x + (size_t)bid * 2048 + t;
        ushort4* dst = (ushort4*)xb + (size_t)bid * 2048 + t;
        #pragma unroll
        for (int i = 0; i < 8; ++i) {
            float4 v = src[i * 256];
            ushort4 o = {f2b(v.x), f2b(v.y), f2b(v.z), f2b(v.w)};
            dst[i * 256] = o;
        }
        return;
    }
    if (bz == 4) {                      // u / vb vectors
        if (blockIdx.y == 0 && blockIdx.x < 2) {
            const int n = blockIdx.x * 256 + t;
            float u = 0.f, v = 0.f;
            #pragma unroll 8
            for (int k = 0; k < 512; ++k) {
                float wv = Wo[(size_t)k * 512 + n];
                u = fmaf(lng[k], wv, u);
                v = fmaf(lnb[k], wv, v);
            }
            U[n] = u; VBc[n] = v + bo[n];
        }
        return;
    }
    // transpose planes
    const float* src = bz == 0 ? W1 : (bz == 1 ? Wv : Wo);
    __hip_bfloat16* dst = bz == 0 ? Wct
                        : (bz == 1 ? Wct + 512 * 512 : Wot);
    const int r0 = blockIdx.y * 32, c0 = blockIdx.x * 32;
    #pragma unroll
    for (int i = 0; i < 4; ++i)
        tile[ty + 8 * i][tx] = src[(size_t)(r0 + ty + 8 * i) * 512 + c0 + tx];
    __syncthreads();
    const float sc = (bz == 2) ? lng[r0 + tx] : 1.f;
    #pragma unroll
    for (int i = 0; i < 4; ++i)
        dst[(size_t)(c0 + ty + 8 * i) * 512 + r0 + tx] =
            __float2bfloat16(tile[tx][ty + 8 * i] * sc);
}

// ---------------------------------------------------------------------------
// bf16 MFMA GEMM: C[M,N] = A[M,512] @ Bt[N,512]^T, BM x 128 tile, 4 waves.
// MODE 0: cols<512 -> outH = bf16(tanh(.+b0)); cols>=512 -> outV = bf16(.+b1)
// MODE 1: fused-LN epilogue: outF = resid + rs*. - rs*mu*u[col] + vb[col]
//         (bias0 = u, bias1 = vb, stats = per-row partial {s,s2} x 2 halves)
// ---------------------------------------------------------------------------
template<int BM, int MODE>
__global__ __launch_bounds__(256) void gemm_mfma(
    const ushort_t* __restrict__ A, const ushort_t* __restrict__ Bt,
    const float* __restrict__ bias0, const float* __restrict__ bias1,
    const float* __restrict__ resid,
    __hip_bfloat16* __restrict__ outH, __hip_bfloat16* __restrict__ outV,
    float* __restrict__ outF, const float* __restrict__ stats)
{
    constexpr int WROWS = BM / 2;
    constexpr int MF    = WROWS / 16;
    constexpr int ACH   = BM / 32;
    __shared__ __align__(16) ushort_t As[BM * 64];
    __shared__ __align__(16) ushort_t Bs[128 * 64];
    __shared__ float muL[BM], rsL[BM];

    const int t  = threadIdx.x;
    const int m0 = blockIdx.y * BM, n0 = blockIdx.x * 128;
    const int l  = t & 63, w = t >> 6;
    const int wr = w >> 1, wc = w & 1;
    const int l15 = l & 15, hi = l >> 4;

    if (MODE == 1 && t < BM) {
        float4 st = *(const float4*)(stats + (size_t)(m0 + t) * 4);
        float s = st.x + st.z, s2 = st.y + st.w;
        float mu = s * (1.f / 512), var = s2 * (1.f / 512) - mu * mu;
        muL[t] = mu;
        rsL[t] = rsqrtf(var + 1e-5f);
    }

    const ushort_t* agp[ACH];
    const ushort_t* bgp[4];
    #pragma unroll
    for (int i = 0; i < ACH; ++i) {
        int row = (t >> 3) + 32 * i, slot = (t & 7) ^ (row & 7);
        agp[i] = A + (size_t)(m0 + row) * 512 + slot * 8;
    }
    #pragma unroll
    for (int i = 0; i < 4; ++i) {
        int row = (t >> 3) + 32 * i, slot = (t & 7) ^ (row & 7);
        bgp[i] = Bt + (size_t)(n0 + row) * 512 + slot * 8;
    }

    int aoff[MF][2], boff[4][2];
    #pragma unroll
    for (int mi = 0; mi < MF; ++mi)
        #pragma unroll
        for (int kh = 0; kh < 2; ++kh) {
            int row = wr * WROWS + mi * 16 + l15;
            aoff[mi][kh] = row * 128 + (((kh * 4 + hi) ^ (row & 7)) * 16);
        }
    #pragma unroll
    for (int nj = 0; nj < 4; ++nj)
        #pragma unroll
        for (int kh = 0; kh < 2; ++kh) {
            int row = wc * 64 + nj * 16 + l15;
            boff[nj][kh] = row * 128 + (((kh * 4 + hi) ^ (row & 7)) * 16);
        }

    f32x4 acc[MF][4];
    #pragma unroll
    for (int mi = 0; mi < MF; ++mi)
        #pragma unroll
        for (int nj = 0; nj < 4; ++nj)
            acc[mi][nj] = f32x4{0.f, 0.f, 0.f, 0.f};

    for (int k0 = 0; k0 < 512; k0 += 64) {
        __syncthreads();
        #pragma unroll
        for (int i = 0; i < ACH; ++i)
            gl_lds16(agp[i] + k0, (char*)As + (size_t)(i * 256 + t) * 16);
        #pragma unroll
        for (int i = 0; i < 4; ++i)
            gl_lds16(bgp[i] + k0, (char*)Bs + (size_t)(i * 256 + t) * 16);
        __syncthreads();
        #pragma unroll
        for (int kh = 0; kh < 2; ++kh) {
            bf16x8 af[MF], bfr[4];
            #pragma unroll
            for (int mi = 0; mi < MF; ++mi)
                af[mi] = *(const bf16x8*)((const char*)As + aoff[mi][kh]);
            #pragma unroll
            for (int nj = 0; nj < 4; ++nj)
                bfr[nj] = *(const bf16x8*)((const char*)Bs + boff[nj][kh]);
            #pragma unroll
            for (int mi = 0; mi < MF; ++mi)
                #pragma unroll
                for (int nj = 0; nj < 4; ++nj)
                    acc[mi][nj] = __builtin_amdgcn_mfma_f32_16x16x32_bf16(
                        af[mi], bfr[nj], acc[mi][nj], 0, 0, 0);
        }
    }

    #pragma unroll
    for (int nj = 0; nj < 4; ++nj) {
        const int gcol = n0 + wc * 64 + nj * 16 + l15;
        if (MODE == 0) {
            const float bsv = (gcol < 512) ? bias0[gcol] : bias1[gcol - 512];
            #pragma unroll
            for (int mi = 0; mi < MF; ++mi)
                #pragma unroll
                for (int r = 0; r < 4; ++r) {
                    const int grow = m0 + wr * WROWS + mi * 16 + hi * 4 + r;
                    float v = acc[mi][nj][r] + bsv;
                    if (gcol < 512)
                        outH[(size_t)grow * 512 + gcol] = __float2bfloat16(tanhf(v));
                    else
                        outV[(size_t)grow * 512 + (gcol - 512)] = __float2bfloat16(v);
                }
        } else {
            const float uN = bias0[gcol], vbN = bias1[gcol];
            #pragma unroll
            for (int mi = 0; mi < MF; ++mi)
                #pragma unroll
                for (int r = 0; r < 4; ++r) {
                    const int rl = wr * WROWS + mi * 16 + hi * 4 + r;
                    const int grow = m0 + rl;
                    const float rs = rsL[rl], mu = muL[rl];
                    outF[(size_t)grow * 512 + gcol] =
                        resid[(size_t)grow * 512 + gcol]
                        + rs * acc[mi][nj][r] - rs * mu * uN + vbN;
                }
        }
    }
}

// ---------------------------------------------------------------------------
// Phase kernel: per row, 32-wide dot vs W2, then phases -> cos/sin (f32).
// ---------------------------------------------------------------------------
__global__ __launch_bounds__(256) void phase_kernel(const __hip_bfloat16* __restrict__ H,
                                                    const float* __restrict__ W2,
                                                    const float* __restrict__ b2,
                                                    const float* __restrict__ ps_p,
                                                    const float* __restrict__ cs_p,
                                                    float* __restrict__ Ca,
                                                    float* __restrict__ Sa)
{
    __shared__ __align__(16) __hip_bfloat16 Hs[8 * DD];
    const int t  = threadIdx.x;
    const int rl = t >> 5;
    const int j  = t & 31;
    const int row0 = blockIdx.x * 8;

    const float4* src = (const float4*)(H + (size_t)row0 * DD);
    float4* dst = (float4*)Hs;
    dst[t] = src[t];
    dst[t + 256] = src[t + 256];
    __syncthreads();

    float dot = 0.f;
    #pragma unroll 8
    for (int d = 0; d < DD; ++d)
        dot = fmaf(__bfloat162float(Hs[rl * DD + d]), W2[d * KK + j], dot);

    const float ps = ps_p[0];
    const float cs = cs_p[0];
    const int gr = row0 + rl;
    const int lpos = gr & (LL - 1);
    const float freq = exp2f(-(float)j * (13.287712379549449f / (float)KK));
    const float content = tanhf(dot + b2[j]) * 3.14159265358979323846f * cs;
    const float total = ps * ((float)lpos * freq) + content;
    float sv, cv;
    sincosf(total, &sv, &cv);
    Ca[(size_t)gr * KK + j] = cv;
    Sa[(size_t)gr * KK + j] = sv;
}

// ---------------------------------------------------------------------------
// Scan pass A (MFMA): PP[bch][d][kk] (bf16, XOR-swizzled octets) where
// kk<32 = sum_l C[l][k]V[l][d], kk>=32 = sum_l S[l][k]V[l][d] per chunk.
// ---------------------------------------------------------------------------
__global__ __launch_bounds__(256) void scanA(const __hip_bfloat16* __restrict__ Vb,
                                             const float* __restrict__ Ca,
                                             const float* __restrict__ Sa,
                                             ushort_t* __restrict__ PPg)
{
    __shared__ __align__(16) ushort_t VT[256 * 40];
    __shared__ __align__(16) ushort_t CT[32 * 40];
    __shared__ __align__(16) ushort_t ST[32 * 40];
    __shared__ __align__(16) ushort_t PPs[256 * 64];
    const int t = threadIdx.x;
    const int bch = blockIdx.x, dh = blockIdx.y;
    const int b = bch >> 6, ch = bch & 63;
    const size_t vbase = ((size_t)b * LL + ch * 32) * DD + dh * 256;

    // stage V^T
    {
        const int lg = t >> 5, dg = t & 31;
        ushort8 r[4];
        #pragma unroll
        for (int i = 0; i < 4; ++i)
            r[i] = *(const ushort8*)((const ushort_t*)Vb + vbase
                                     + (size_t)(lg * 4 + i) * DD + dg * 8);
        #pragma unroll
        for (int jd = 0; jd < 8; ++jd) {
            ushort4 w4 = {r[0][jd], r[1][jd], r[2][jd], r[3][jd]};
            *(ushort4*)&VT[(dg * 8 + jd) * 40 + lg * 4] = w4;
        }
    }
    // stage C^T/S^T (bf16)
    if (t < 64) {
        const float* srcp = (t < 32) ? Ca : Sa;
        ushort_t* dstp = (t < 32) ? CT : ST;
        const int tt = t & 31;
        const int kg = tt >> 2, lgg = tt & 3;
        float4 v[8];
        #pragma unroll
        for (int i = 0; i < 8; ++i)
            v[i] = *(const float4*)(srcp
                    + ((size_t)b * LL + ch * 32 + lgg * 8 + i) * KK + kg * 4);
        #pragma unroll
        for (int kk2 = 0; kk2 < 4; ++kk2) {
            ushort8 w8;
            #pragma unroll
            for (int i = 0; i < 8; ++i) w8[i] = f2b(((const float*)&v[i])[kk2]);
            *(ushort8*)&dstp[(kg * 4 + kk2) * 40 + lgg * 8] = w8;
        }
    }
    __syncthreads();

    const int w = t >> 6, l = t & 63, l15 = l & 15, hi = l >> 4;
    bf16x8 afc[2], afs[2];
    #pragma unroll
    for (int mt = 0; mt < 2; ++mt) {
        afc[mt] = *(const bf16x8*)&CT[(l15 + 16 * mt) * 40 + hi * 8];
        afs[mt] = *(const bf16x8*)&ST[(l15 + 16 * mt) * 40 + hi * 8];
    }
    f32x4 aPR[2][4], aPI[2][4];
    #pragma unroll
    for (int mt = 0; mt < 2; ++mt)
        #pragma unroll
        for (int nt = 0; nt < 4; ++nt) {
            aPR[mt][nt] = f32x4{0.f,0.f,0.f,0.f};
            aPI[mt][nt] = f32x4{0.f,0.f,0.f,0.f};
        }
    #pragma unroll
    for (int nt = 0; nt < 4; ++nt) {
        bf16x8 bv = *(const bf16x8*)&VT[(w * 64 + nt * 16 + l15) * 40 + hi * 8];
        #pragma unroll
        for (int mt = 0; mt < 2; ++mt) {
            aPR[mt][nt] = __builtin_amdgcn_mfma_f32_16x16x32_bf16(afc[mt], bv, aPR[mt][nt], 0,0,0);
            aPI[mt][nt] = __builtin_amdgcn_mfma_f32_16x16x32_bf16(afs[mt], bv, aPI[mt][nt], 0,0,0);
        }
    }
    // transpose to [d][kk] bf16 in LDS (swizzled octets), then coalesced copyout
    #pragma unroll
    for (int mt = 0; mt < 2; ++mt)
        #pragma unroll
        for (int nt = 0; nt < 4; ++nt) {
            const int dloc = w * 64 + nt * 16 + l15;
            const int kq = 16 * mt + hi * 4;
            const int oR = kq >> 3, oI = 4 + (kq >> 3);
            const int sub = (hi & 1) * 4;
            ushort4 pr4 = {f2b(aPR[mt][nt][0]), f2b(aPR[mt][nt][1]),
                           f2b(aPR[mt][nt][2]), f2b(aPR[mt][nt][3])};
            ushort4 pi4 = {f2b(aPI[mt][nt][0]), f2b(aPI[mt][nt][1]),
                           f2b(aPI[mt][nt][2]), f2b(aPI[mt][nt][3])};
            *(ushort4*)&PPs[dloc * 64 + ((oR ^ (dloc & 7)) * 8) + sub] = pr4;
            *(ushort4*)&PPs[dloc * 64 + ((oI ^ (dloc & 7)) * 8) + sub] = pi4;
        }
    __syncthreads();
    ushort_t* gout = PPg + ((size_t)bch * 512 + dh * 256) * 64;
    #pragma unroll
    for (int i = 0; i < 8; ++i)
        *(ushort8*)(gout + (size_t)(i * 256 + t) * 8) =
            *(const ushort8*)&PPs[(i * 256 + t) * 8];
}

// ---------------------------------------------------------------------------
// Scan pass B: exclusive prefix over 64 chunks on bf16 PP (f32 accumulate).
// Swizzle-transparent (same permutation every chunk). 64 blocks x 256.
// ---------------------------------------------------------------------------
__global__ __launch_bounds__(256) void scan_prefix(ushort_t* __restrict__ PPg)
{
    const int g = blockIdx.x * 256 + threadIdx.x;   // 0..16383
    const int b = g >> 13, p = g & 8191;
    float run0 = 0.f, run1 = 0.f, run2 = 0.f, run3 = 0.f;
    for (int gg = 0; gg < 4; ++gg) {
        ushort4 v[16];
        #pragma unroll
        for (int i = 0; i < 16; ++i)
            v[i] = *(const ushort4*)(PPg + (size_t)(b * 64 + gg * 16 + i) * 32768 + p * 4);
        #pragma unroll
        for (int i = 0; i < 16; ++i) {
            ushort4 o = {f2b(run0), f2b(run1), f2b(run2), f2b(run3)};
            run0 += b2f(v[i].x); run1 += b2f(v[i].y);
            run2 += b2f(v[i].z); run3 += b2f(v[i].w);
            *(ushort4*)(PPg + (size_t)(b * 64 + gg * 16 + i) * 32768 + p * 4) = o;
        }
    }
}

// ---------------------------------------------------------------------------
// Scan pass C (MFMA): ret = [C|S]@PPpre + tri(G)@V, scale, write bf16 over Vb.
// Also emits per-row partial LN stats {sum, sumsq} per d-half.
// ---------------------------------------------------------------------------
__global__ __launch_bounds__(256) void scanC(__hip_bfloat16* Vb,
                                             const float* __restrict__ Ca,
                                             const float* __restrict__ Sa,
                                             const ushort_t* __restrict__ PPg,
                                             float* __restrict__ StatsG)
{
    __shared__ __align__(16) ushort_t VT[256 * 40];   // [d][l], pad->40
    __shared__ __align__(16) ushort_t PPT[256 * 64];  // [d][kk], swizzled octets
    __shared__ __align__(16) ushort_t CS[32 * 80];    // [l][c|s], pad->80
    __shared__ __align__(16) ushort_t G[32 * 40];     // [l][l'], pad->40
    __shared__ __align__(16) ushort_t RT[4][32 * 64]; // per-wave ret slab
    __shared__ float2 statsL[4][32];

    const int t = threadIdx.x;
    const int bch = blockIdx.x, dh = blockIdx.y;
    const int b = bch >> 6, ch = bch & 63;
    const size_t vbase = ((size_t)b * LL + ch * 32) * DD + dh * 256;

    // stage PPT via async direct-to-LDS (already transposed+swizzled in global)
    {
        const ushort_t* ppg = PPg + ((size_t)bch * 512 + dh * 256) * 64;
        #pragma unroll
        for (int i = 0; i < 8; ++i)
            gl_lds16(ppg + (size_t)(i * 256 + t) * 8,
                     (char*)PPT + (size_t)(i * 256 + t) * 16);
    }
    // stage V^T
    {
        const int lg = t >> 5, dg = t & 31;
        ushort8 r[4];
        #pragma unroll
        for (int i = 0; i < 4; ++i)
            r[i] = *(const ushort8*)((const ushort_t*)Vb + vbase
                                     + (size_t)(lg * 4 + i) * DD + dg * 8);
        #pragma unroll
        for (int jd = 0; jd < 8; ++jd) {
            ushort4 w4 = {r[0][jd], r[1][jd], r[2][jd], r[3][jd]};
            *(ushort4*)&VT[(dg * 8 + jd) * 40 + lg * 4] = w4;
        }
    }
    // stage CS rows
    {
        const int half = t >> 7;
        const int tt = t & 127;
        const int lrow = tt >> 2, kq = tt & 3;
        const float* srcp = half ? Sa : Ca;
        float4 v0 = *(const float4*)(srcp + ((size_t)b * LL + ch * 32 + lrow) * KK + kq * 8);
        float4 v1 = *(const float4*)(srcp + ((size_t)b * LL + ch * 32 + lrow) * KK + kq * 8 + 4);
        ushort8 w8 = {f2b(v0.x), f2b(v0.y), f2b(v0.z), f2b(v0.w),
                      f2b(v1.x), f2b(v1.y), f2b(v1.z), f2b(v1.w)};
        *(ushort8*)&CS[lrow * 80 + half * 32 + kq * 8] = w8;
    }
    __syncthreads();

    const int w = t >> 6, l = t & 63, l15 = l & 15, hi = l >> 4;

    // G = tri(C@C^T + S@S^T)
    {
        bf16x8 fc[2], fs[2];
        #pragma unroll
        for (int mt = 0; mt < 2; ++mt) {
            fc[mt] = *(const bf16x8*)&CS[(l15 + 16 * mt) * 80 + hi * 8];
            fs[mt] = *(const bf16x8*)&CS[(l15 + 16 * mt) * 80 + 32 + hi * 8];
        }
        f32x4 gacc[2][2];
        #pragma unroll
        for (int mt = 0; mt < 2; ++mt)
            #pragma unroll
            for (int nt = 0; nt < 2; ++nt) {
                gacc[mt][nt] = f32x4{0.f,0.f,0.f,0.f};
                gacc[mt][nt] = __builtin_amdgcn_mfma_f32_16x16x32_bf16(fc[mt], fc[nt], gacc[mt][nt], 0,0,0);
                gacc[mt][nt] = __builtin_amdgcn_mfma_f32_16x16x32_bf16(fs[mt], fs[nt], gacc[mt][nt], 0,0,0);
            }
        #pragma unroll
        for (int mt = 0; mt < 2; ++mt)
            #pragma unroll
            for (int nt = 0; nt < 2; ++nt)
                #pragma unroll
                for (int r = 0; r < 4; ++r) {
                    const int row = 16 * mt + hi * 4 + r;
                    const int col = 16 * nt + l15;
                    float gv = (col <= row) ? gacc[mt][nt][r] : 0.f;
                    G[row * 40 + col] = f2b(gv);
                }
    }

    // main accumulation
    bf16x8 a1[2][2], ag[2];
    #pragma unroll
    for (int mt = 0; mt < 2; ++mt) {
        a1[mt][0] = *(const bf16x8*)&CS[(l15 + 16 * mt) * 80 + hi * 8];
        a1[mt][1] = *(const bf16x8*)&CS[(l15 + 16 * mt) * 80 + 32 + hi * 8];
        ag[mt]    = *(const bf16x8*)&G[(l15 + 16 * mt) * 40 + hi * 8];
    }
    f32x4 acc[2][4];
    #pragma unroll
    for (int mt = 0; mt < 2; ++mt)
        #pragma unroll
        for (int nt = 0; nt < 4; ++nt)
            acc[mt][nt] = f32x4{0.f,0.f,0.f,0.f};
    #pragma unroll
    for (int nt = 0; nt < 4; ++nt) {
        const int drow = w * 64 + nt * 16 + l15;
        bf16x8 bp0 = *(const bf16x8*)((const char*)PPT + drow * 128 + ((hi ^ (drow & 7)) << 4));
        bf16x8 bp1 = *(const bf16x8*)((const char*)PPT + drow * 128 + (((4 + hi) ^ (drow & 7)) << 4));
        bf16x8 bv  = *(const bf16x8*)&VT[drow * 40 + hi * 8];
        #pragma unroll
        for (int mt = 0; mt < 2; ++mt) {
            acc[mt][nt] = __builtin_amdgcn_mfma_f32_16x16x32_bf16(a1[mt][0], bp0, acc[mt][nt], 0,0,0);
            acc[mt][nt] = __builtin_amdgcn_mfma_f32_16x16x32_bf16(a1[mt][1], bp1, acc[mt][nt], 0,0,0);
            acc[mt][nt] = __builtin_amdgcn_mfma_f32_16x16x32_bf16(ag[mt],    bv,  acc[mt][nt], 0,0,0);
        }
    }

    // epilogue: scale + stats accumulate + RT slab
    float sP[2][4] = {}, qP[2][4] = {};
    #pragma unroll
    for (int mt = 0; mt < 2; ++mt)
        #pragma unroll
        for (int nt = 0; nt < 4; ++nt)
            #pragma unroll
            for (int r = 0; r < 4; ++r) {
                const int lrow = 16 * mt + hi * 4 + r;
                const float scale = rsqrtf((float)((ch * 32 + lrow + 1) * KK));
                const float val = acc[mt][nt][r] * scale;
                sP[mt][r] += val;
                qP[mt][r] = fmaf(val, val, qP[mt][r]);
                RT[w][lrow * 64 + nt * 16 + l15] = f2b(val);
            }
    // coalesced in-place store (wave-local)
    #pragma unroll
    for (int c = 0; c < 4; ++c) {
        const int cid = c * 64 + l;
        const int row = cid >> 3, c8 = cid & 7;
        ushort8 v = *(const ushort8*)&RT[w][row * 64 + c8 * 8];
        *(ushort8*)((ushort_t*)Vb + ((size_t)b * LL + ch * 32 + row) * DD
                    + dh * 256 + w * 64 + c8 * 8) = v;
    }
    // stats: reduce over the 16-lane (l15) group, combine waves via LDS
    #pragma unroll
    for (int mt = 0; mt < 2; ++mt)
        #pragma unroll
        for (int r = 0; r < 4; ++r) {
            float sv = sP[mt][r], qv = qP[mt][r];
            #pragma unroll
            for (int off = 1; off < 16; off <<= 1) {
                sv += __shfl_xor(sv, off);
                qv += __shfl_xor(qv, off);
            }
            if (l15 == 0)
                statsL[w][16 * mt + hi * 4 + r] = float2{sv, qv};
        }
    __syncthreads();
    if (t < 32) {
        float s = 0.f, q = 0.f;
        #pragma unroll
        for (int w4 = 0; w4 < 4; ++w4) {
            float2 p = statsL[w4][t];
            s += p.x; q += p.y;
        }
        const size_t rowg = (size_t)b * LL + ch * 32 + t;
        *(float2*)&StatsG[(rowg * 2 + dh) * 2] = float2{s, q};
    }
}

// ---------------------------------------------------------------------------
extern "C" void kernel_launch(void* const* d_in, const int* in_sizes, int n_in,
                              void* d_out, int out_size, void* d_ws, size_t ws_size,
                              hipStream_t stream)
{
    const float* x   = (const float*)d_in[0];
    const float* W1  = (const float*)d_in[1];
    const float* b1  = (const float*)d_in[2];
    const float* W2  = (const float*)d_in[3];
    const float* b2  = (const float*)d_in[4];
    const float* ps  = (const float*)d_in[5];
    const float* cs  = (const float*)d_in[6];
    const float* Wv  = (const float*)d_in[7];
    const float* bv  = (const float*)d_in[8];
    const float* lng = (const float*)d_in[9];
    const float* lnb = (const float*)d_in[10];
    const float* Wo  = (const float*)d_in[11];
    const float* bo  = (const float*)d_in[12];
    float* out = (float*)d_out;

    char* wsb = (char*)d_ws;
    __hip_bfloat16* Vb  = (__hip_bfloat16*)(wsb);                     // 4 MB
    ushort_t* PPg = (ushort_t*)(wsb + (4u << 20));                    // 8 MB
    float* Ca  = (float*)(wsb + (12u << 20));                         // 512 KB
    float* Sa  = (float*)(wsb + (12u << 20) + (512u << 10));          // 512 KB
    __hip_bfloat16* xb  = (__hip_bfloat16*)(wsb + (13u << 20));       // 4 MB
    __hip_bfloat16* Hb  = (__hip_bfloat16*)(wsb + (17u << 20));       // 4 MB
    __hip_bfloat16* Wct = (__hip_bfloat16*)(wsb + (21u << 20));       // 1 MB
    __hip_bfloat16* Wot = (__hip_bfloat16*)(wsb + (22u << 20));       // 0.5 MB
    float* StatsG = (float*)(wsb + (23u << 20));                      // 64 KB
    float* U      = (float*)(wsb + (23u << 20) + (64u << 10));        // 2 KB
    float* VBc    = (float*)(wsb + (23u << 20) + (66u << 10));        // 2 KB

    prep<<<dim3(16, 16, 5), dim3(32, 8), 0, stream>>>(
        W1, Wv, Wo, x, lng, lnb, bo, Wct, Wot, xb, U, VBc);
    gemm_mfma<128, 0><<<dim3(8, 32), dim3(256), 0, stream>>>(
        (const ushort_t*)xb, (const ushort_t*)Wct, b1, bv, nullptr, Hb, Vb, nullptr, nullptr);
    phase_kernel<<<dim3(BL / 8), dim3(256), 0, stream>>>(Hb, W2, b2, ps, cs, Ca, Sa);
    scanA<<<dim3(BB * NCH, 2), dim3(256), 0, stream>>>(Vb, Ca, Sa, PPg);
    scan_prefix<<<dim3(64), dim3(256), 0, stream>>>(PPg);
    scanC<<<dim3(BB * NCH, 2), dim3(256), 0, stream>>>(Vb, Ca, Sa, PPg, StatsG);
    gemm_mfma<64, 1><<<dim3(4, 64), dim3(256), 0, stream>>>(
        (const ushort_t*)Vb, (const ushort_t*)Wot, U, VBc, x, nullptr, nullptr, out, StatsG);
}

// Round 5
// 86.049 us; speedup vs baseline: 1.1673x; 1.1673x over previous
//
#include <hip/hip_runtime.h>
#include <hip/hip_bf16.h>
#include <math.h>

// Problem constants
#define BB   2
#define LL   2048
#define DD   512
#define KK   32
#define BL   (BB*LL)      // 4096
#define NCH  64           // chunks along L
#define LC   32           // rows per chunk

typedef unsigned short ushort_t;
typedef __bf16 bf16x8 __attribute__((ext_vector_type(8)));
typedef float  f32x4  __attribute__((ext_vector_type(4)));
typedef unsigned short ushort8 __attribute__((ext_vector_type(8)));

__device__ __forceinline__ void gl_lds16(const void* g, void* l) {
    __builtin_amdgcn_global_load_lds(
        (const __attribute__((address_space(1))) void*)g,
        (__attribute__((address_space(3))) void*)l, 16, 0, 0);
}
__device__ __forceinline__ ushort_t f2b(float f) {
    __bf16 b = (__bf16)f; return *(ushort_t*)&b;
}
__device__ __forceinline__ float b2f(ushort_t u) {
    unsigned int x = ((unsigned int)u) << 16; return *(float*)&x;
}

// ---------------------------------------------------------------------------
// prep: z=0: W1^T->Wct[0:512]; z=1: Wv^T->Wct[512:]; z=2: (g.Wo)^T->Wot;
//       z=3: cast x->xb; z=4: U[n]+=sum_k g[k]Wo[k][n] (16 k-panel blocks,
//       atomicAdd; U/VBc pre-zeroed by hipMemsetAsync)
// ---------------------------------------------------------------------------
__global__ __launch_bounds__(256) void prep(const float* __restrict__ W1,
                                            const float* __restrict__ Wv,
                                            const float* __restrict__ Wo,
                                            const float* __restrict__ x,
                                            const float* __restrict__ lng,
                                            const float* __restrict__ lnb,
                                            const float* __restrict__ bo,
                                            __hip_bfloat16* __restrict__ Wct,
                                            __hip_bfloat16* __restrict__ Wot,
                                            __hip_bfloat16* __restrict__ xb,
                                            float* __restrict__ U,
                                            float* __restrict__ VBc)
{
    __shared__ float tile[32][33];
    const int bz = blockIdx.z;
    const int tx = threadIdx.x, ty = threadIdx.y;
    const int t = ty * 32 + tx;

    if (bz == 3) {                      // cast x (2M floats): 256 blocks
        const int bid = blockIdx.y * 16 + blockIdx.x;
        const float4* src = (const float4*)x + (size_t)bid * 2048 + t;
        ushort4* dst = (ushort4*)xb + (size_t)bid * 2048 + t;
        #pragma unroll
        for (int i = 0; i < 8; ++i) {
            float4 v = src[i * 256];
            ushort4 o = {f2b(v.x), f2b(v.y), f2b(v.z), f2b(v.w)};
            dst[i * 256] = o;
        }
        return;
    }
    if (bz == 4) {                      // u / vb: 16 k-panel blocks, coalesced
        if (blockIdx.x != 0) return;
        const int kg = blockIdx.y;      // 0..15
        const int k0 = kg * 32;
        float u0 = 0.f, u1 = 0.f, v0 = 0.f, v1 = 0.f;
        #pragma unroll 4
        for (int k = 0; k < 32; ++k) {
            const float g1 = lng[k0 + k], b1v = lnb[k0 + k];
            const float w0 = Wo[(size_t)(k0 + k) * 512 + t];
            const float w1 = Wo[(size_t)(k0 + k) * 512 + t + 256];
            u0 = fmaf(g1, w0, u0);  u1 = fmaf(g1, w1, u1);
            v0 = fmaf(b1v, w0, v0); v1 = fmaf(b1v, w1, v1);
        }
        if (kg == 0) { v0 += bo[t]; v1 += bo[t + 256]; }
        atomicAdd(&U[t], u0);         atomicAdd(&U[t + 256], u1);
        atomicAdd(&VBc[t], v0);       atomicAdd(&VBc[t + 256], v1);
        return;
    }
    // transpose planes
    const float* src = bz == 0 ? W1 : (bz == 1 ? Wv : Wo);
    __hip_bfloat16* dst = bz == 0 ? Wct
                        : (bz == 1 ? Wct + 512 * 512 : Wot);
    const int r0 = blockIdx.y * 32, c0 = blockIdx.x * 32;
    #pragma unroll
    for (int i = 0; i < 4; ++i)
        tile[ty + 8 * i][tx] = src[(size_t)(r0 + ty + 8 * i) * 512 + c0 + tx];
    __syncthreads();
    const float sc = (bz == 2) ? lng[r0 + tx] : 1.f;
    #pragma unroll
    for (int i = 0; i < 4; ++i)
        dst[(size_t)(c0 + ty + 8 * i) * 512 + r0 + tx] =
            __float2bfloat16(tile[tx][ty + 8 * i] * sc);
}

// ---------------------------------------------------------------------------
// bf16 MFMA GEMM: C[M,N] = A[M,512] @ Bt[N,512]^T, BM x 128 tile, 4 waves.
// MODE 0: cols<512 -> outH = bf16(tanh(.+b0)); cols>=512 -> outV = bf16(.+b1)
// MODE 1: fused-LN epilogue: outF = resid + rs*. - rs*mu*u[col] + vb[col]
// ---------------------------------------------------------------------------
template<int BM, int MODE>
__global__ __launch_bounds__(256) void gemm_mfma(
    const ushort_t* __restrict__ A, const ushort_t* __restrict__ Bt,
    const float* __restrict__ bias0, const float* __restrict__ bias1,
    const float* __restrict__ resid,
    __hip_bfloat16* __restrict__ outH, __hip_bfloat16* __restrict__ outV,
    float* __restrict__ outF, const float* __restrict__ stats)
{
    constexpr int WROWS = BM / 2;
    constexpr int MF    = WROWS / 16;
    constexpr int ACH   = BM / 32;
    __shared__ __align__(16) ushort_t As[BM * 64];
    __shared__ __align__(16) ushort_t Bs[128 * 64];
    __shared__ float muL[BM], rsL[BM];

    const int t  = threadIdx.x;
    const int m0 = blockIdx.y * BM, n0 = blockIdx.x * 128;
    const int l  = t & 63, w = t >> 6;
    const int wr = w >> 1, wc = w & 1;
    const int l15 = l & 15, hi = l >> 4;

    if (MODE == 1 && t < BM) {
        float4 st = *(const float4*)(stats + (size_t)(m0 + t) * 4);
        float s = st.x + st.z, s2 = st.y + st.w;
        float mu = s * (1.f / 512), var = s2 * (1.f / 512) - mu * mu;
        muL[t] = mu;
        rsL[t] = rsqrtf(var + 1e-5f);
    }

    const ushort_t* agp[ACH];
    const ushort_t* bgp[4];
    #pragma unroll
    for (int i = 0; i < ACH; ++i) {
        int row = (t >> 3) + 32 * i, slot = (t & 7) ^ (row & 7);
        agp[i] = A + (size_t)(m0 + row) * 512 + slot * 8;
    }
    #pragma unroll
    for (int i = 0; i < 4; ++i) {
        int row = (t >> 3) + 32 * i, slot = (t & 7) ^ (row & 7);
        bgp[i] = Bt + (size_t)(n0 + row) * 512 + slot * 8;
    }

    int aoff[MF][2], boff[4][2];
    #pragma unroll
    for (int mi = 0; mi < MF; ++mi)
        #pragma unroll
        for (int kh = 0; kh < 2; ++kh) {
            int row = wr * WROWS + mi * 16 + l15;
            aoff[mi][kh] = row * 128 + (((kh * 4 + hi) ^ (row & 7)) * 16);
        }
    #pragma unroll
    for (int nj = 0; nj < 4; ++nj)
        #pragma unroll
        for (int kh = 0; kh < 2; ++kh) {
            int row = wc * 64 + nj * 16 + l15;
            boff[nj][kh] = row * 128 + (((kh * 4 + hi) ^ (row & 7)) * 16);
        }

    f32x4 acc[MF][4];
    #pragma unroll
    for (int mi = 0; mi < MF; ++mi)
        #pragma unroll
        for (int nj = 0; nj < 4; ++nj)
            acc[mi][nj] = f32x4{0.f, 0.f, 0.f, 0.f};

    for (int k0 = 0; k0 < 512; k0 += 64) {
        __syncthreads();
        #pragma unroll
        for (int i = 0; i < ACH; ++i)
            gl_lds16(agp[i] + k0, (char*)As + (size_t)(i * 256 + t) * 16);
        #pragma unroll
        for (int i = 0; i < 4; ++i)
            gl_lds16(bgp[i] + k0, (char*)Bs + (size_t)(i * 256 + t) * 16);
        __syncthreads();
        #pragma unroll
        for (int kh = 0; kh < 2; ++kh) {
            bf16x8 af[MF], bfr[4];
            #pragma unroll
            for (int mi = 0; mi < MF; ++mi)
                af[mi] = *(const bf16x8*)((const char*)As + aoff[mi][kh]);
            #pragma unroll
            for (int nj = 0; nj < 4; ++nj)
                bfr[nj] = *(const bf16x8*)((const char*)Bs + boff[nj][kh]);
            #pragma unroll
            for (int mi = 0; mi < MF; ++mi)
                #pragma unroll
                for (int nj = 0; nj < 4; ++nj)
                    acc[mi][nj] = __builtin_amdgcn_mfma_f32_16x16x32_bf16(
                        af[mi], bfr[nj], acc[mi][nj], 0, 0, 0);
        }
    }

    #pragma unroll
    for (int nj = 0; nj < 4; ++nj) {
        const int gcol = n0 + wc * 64 + nj * 16 + l15;
        if (MODE == 0) {
            const float bsv = (gcol < 512) ? bias0[gcol] : bias1[gcol - 512];
            #pragma unroll
            for (int mi = 0; mi < MF; ++mi)
                #pragma unroll
                for (int r = 0; r < 4; ++r) {
                    const int grow = m0 + wr * WROWS + mi * 16 + hi * 4 + r;
                    float v = acc[mi][nj][r] + bsv;
                    if (gcol < 512)
                        outH[(size_t)grow * 512 + gcol] = __float2bfloat16(tanhf(v));
                    else
                        outV[(size_t)grow * 512 + (gcol - 512)] = __float2bfloat16(v);
                }
        } else {
            const float uN = bias0[gcol], vbN = bias1[gcol];
            #pragma unroll
            for (int mi = 0; mi < MF; ++mi)
                #pragma unroll
                for (int r = 0; r < 4; ++r) {
                    const int rl = wr * WROWS + mi * 16 + hi * 4 + r;
                    const int grow = m0 + rl;
                    const float rs = rsL[rl], mu = muL[rl];
                    outF[(size_t)grow * 512 + gcol] =
                        resid[(size_t)grow * 512 + gcol]
                        + rs * acc[mi][nj][r] - rs * mu * uN + vbN;
                }
        }
    }
}

// ---------------------------------------------------------------------------
// Phase kernel: per row, 32-wide dot vs W2, then phases -> cos/sin (f32).
// ---------------------------------------------------------------------------
__global__ __launch_bounds__(256) void phase_kernel(const __hip_bfloat16* __restrict__ H,
                                                    const float* __restrict__ W2,
                                                    const float* __restrict__ b2,
                                                    const float* __restrict__ ps_p,
                                                    const float* __restrict__ cs_p,
                                                    float* __restrict__ Ca,
                                                    float* __restrict__ Sa)
{
    __shared__ __align__(16) __hip_bfloat16 Hs[8 * DD];
    const int t  = threadIdx.x;
    const int rl = t >> 5;
    const int j  = t & 31;
    const int row0 = blockIdx.x * 8;

    const float4* src = (const float4*)(H + (size_t)row0 * DD);
    float4* dst = (float4*)Hs;
    dst[t] = src[t];
    dst[t + 256] = src[t + 256];
    __syncthreads();

    float dot = 0.f;
    #pragma unroll 8
    for (int d = 0; d < DD; ++d)
        dot = fmaf(__bfloat162float(Hs[rl * DD + d]), W2[d * KK + j], dot);

    const float ps = ps_p[0];
    const float cs = cs_p[0];
    const int gr = row0 + rl;
    const int lpos = gr & (LL - 1);
    const float freq = exp2f(-(float)j * (13.287712379549449f / (float)KK));
    const float content = tanhf(dot + b2[j]) * 3.14159265358979323846f * cs;
    const float total = ps * ((float)lpos * freq) + content;
    float sv, cv;
    sincosf(total, &sv, &cv);
    Ca[(size_t)gr * KK + j] = cv;
    Sa[(size_t)gr * KK + j] = sv;
}

// ---------------------------------------------------------------------------
// Scan pass A (MFMA): PP[bch][d][kk] (bf16, XOR-swizzled octets) where
// kk<32 = sum_l C[l][k]V[l][d], kk>=32 = sum_l S[l][k]V[l][d] per chunk.
// ---------------------------------------------------------------------------
__global__ __launch_bounds__(256) void scanA(const __hip_bfloat16* __restrict__ Vb,
                                             const float* __restrict__ Ca,
                                             const float* __restrict__ Sa,
                                             ushort_t* __restrict__ PPg)
{
    __shared__ __align__(16) ushort_t VT[256 * 40];
    __shared__ __align__(16) ushort_t CT[32 * 40];
    __shared__ __align__(16) ushort_t ST[32 * 40];
    __shared__ __align__(16) ushort_t PPs[256 * 64];
    const int t = threadIdx.x;
    const int bch = blockIdx.x, dh = blockIdx.y;
    const int b = bch >> 6, ch = bch & 63;
    const size_t vbase = ((size_t)b * LL + ch * 32) * DD + dh * 256;

    // stage V^T
    {
        const int lg = t >> 5, dg = t & 31;
        ushort8 r[4];
        #pragma unroll
        for (int i = 0; i < 4; ++i)
            r[i] = *(const ushort8*)((const ushort_t*)Vb + vbase
                                     + (size_t)(lg * 4 + i) * DD + dg * 8);
        #pragma unroll
        for (int jd = 0; jd < 8; ++jd) {
            ushort4 w4 = {r[0][jd], r[1][jd], r[2][jd], r[3][jd]};
            *(ushort4*)&VT[(dg * 8 + jd) * 40 + lg * 4] = w4;
        }
    }
    // stage C^T/S^T (bf16)
    if (t < 64) {
        const float* srcp = (t < 32) ? Ca : Sa;
        ushort_t* dstp = (t < 32) ? CT : ST;
        const int tt = t & 31;
        const int kg = tt >> 2, lgg = tt & 3;
        float4 v[8];
        #pragma unroll
        for (int i = 0; i < 8; ++i)
            v[i] = *(const float4*)(srcp
                    + ((size_t)b * LL + ch * 32 + lgg * 8 + i) * KK + kg * 4);
        #pragma unroll
        for (int kk2 = 0; kk2 < 4; ++kk2) {
            ushort8 w8;
            #pragma unroll
            for (int i = 0; i < 8; ++i) w8[i] = f2b(((const float*)&v[i])[kk2]);
            *(ushort8*)&dstp[(kg * 4 + kk2) * 40 + lgg * 8] = w8;
        }
    }
    __syncthreads();

    const int w = t >> 6, l = t & 63, l15 = l & 15, hi = l >> 4;
    bf16x8 afc[2], afs[2];
    #pragma unroll
    for (int mt = 0; mt < 2; ++mt) {
        afc[mt] = *(const bf16x8*)&CT[(l15 + 16 * mt) * 40 + hi * 8];
        afs[mt] = *(const bf16x8*)&ST[(l15 + 16 * mt) * 40 + hi * 8];
    }
    f32x4 aPR[2][4], aPI[2][4];
    #pragma unroll
    for (int mt = 0; mt < 2; ++mt)
        #pragma unroll
        for (int nt = 0; nt < 4; ++nt) {
            aPR[mt][nt] = f32x4{0.f,0.f,0.f,0.f};
            aPI[mt][nt] = f32x4{0.f,0.f,0.f,0.f};
        }
    #pragma unroll
    for (int nt = 0; nt < 4; ++nt) {
        bf16x8 bv = *(const bf16x8*)&VT[(w * 64 + nt * 16 + l15) * 40 + hi * 8];
        #pragma unroll
        for (int mt = 0; mt < 2; ++mt) {
            aPR[mt][nt] = __builtin_amdgcn_mfma_f32_16x16x32_bf16(afc[mt], bv, aPR[mt][nt], 0,0,0);
            aPI[mt][nt] = __builtin_amdgcn_mfma_f32_16x16x32_bf16(afs[mt], bv, aPI[mt][nt], 0,0,0);
        }
    }
    // transpose to [d][kk] bf16 in LDS (swizzled octets), then coalesced copyout
    #pragma unroll
    for (int mt = 0; mt < 2; ++mt)
        #pragma unroll
        for (int nt = 0; nt < 4; ++nt) {
            const int dloc = w * 64 + nt * 16 + l15;
            const int kq = 16 * mt + hi * 4;
            const int oR = kq >> 3, oI = 4 + (kq >> 3);
            const int sub = (hi & 1) * 4;
            ushort4 pr4 = {f2b(aPR[mt][nt][0]), f2b(aPR[mt][nt][1]),
                           f2b(aPR[mt][nt][2]), f2b(aPR[mt][nt][3])};
            ushort4 pi4 = {f2b(aPI[mt][nt][0]), f2b(aPI[mt][nt][1]),
                           f2b(aPI[mt][nt][2]), f2b(aPI[mt][nt][3])};
            *(ushort4*)&PPs[dloc * 64 + ((oR ^ (dloc & 7)) * 8) + sub] = pr4;
            *(ushort4*)&PPs[dloc * 64 + ((oI ^ (dloc & 7)) * 8) + sub] = pi4;
        }
    __syncthreads();
    ushort_t* gout = PPg + ((size_t)bch * 512 + dh * 256) * 64;
    #pragma unroll
    for (int i = 0; i < 8; ++i)
        *(ushort8*)(gout + (size_t)(i * 256 + t) * 8) =
            *(const ushort8*)&PPs[(i * 256 + t) * 8];
}

// ---------------------------------------------------------------------------
// Scan pass B: exclusive prefix over 64 chunks on bf16 PP (f32 accumulate).
// uint (ushort2) granularity -> 32768 threads / 128 blocks for latency hiding.
// ---------------------------------------------------------------------------
__global__ __launch_bounds__(256) void scan_prefix(ushort_t* __restrict__ PPg)
{
    const int g = blockIdx.x * 256 + threadIdx.x;   // 0..32767
    const int b = g >> 14, p = g & 16383;           // p: ushort2 index within b
    float run0 = 0.f, run1 = 0.f;
    for (int gg = 0; gg < 4; ++gg) {
        unsigned int v[16];
        #pragma unroll
        for (int i = 0; i < 16; ++i)
            v[i] = *(const unsigned int*)(PPg + (size_t)(b * 64 + gg * 16 + i) * 32768 + p * 2);
        #pragma unroll
        for (int i = 0; i < 16; ++i) {
            unsigned int o = (unsigned int)f2b(run0) | ((unsigned int)f2b(run1) << 16);
            run0 += b2f((ushort_t)(v[i] & 0xffffu));
            run1 += b2f((ushort_t)(v[i] >> 16));
            *(unsigned int*)(PPg + (size_t)(b * 64 + gg * 16 + i) * 32768 + p * 2) = o;
        }
    }
}

// ---------------------------------------------------------------------------
// Scan pass C (MFMA): ret = [C|S]@PPpre + tri(G)@V, scale, write bf16 over Vb.
// Also emits per-row partial LN stats {sum, sumsq} per d-half.
// ---------------------------------------------------------------------------
__global__ __launch_bounds__(256) void scanC(__hip_bfloat16* Vb,
                                             const float* __restrict__ Ca,
                                             const float* __restrict__ Sa,
                                             const ushort_t* __restrict__ PPg,
                                             float* __restrict__ StatsG)
{
    __shared__ __align__(16) ushort_t VT[256 * 40];   // [d][l], pad->40
    __shared__ __align__(16) ushort_t PPT[256 * 64];  // [d][kk], swizzled octets
    __shared__ __align__(16) ushort_t CS[32 * 80];    // [l][c|s], pad->80
    __shared__ __align__(16) ushort_t G[32 * 40];     // [l][l'], pad->40
    __shared__ __align__(16) ushort_t RT[4][32 * 64]; // per-wave ret slab
    __shared__ float2 statsL[4][32];

    const int t = threadIdx.x;
    const int bch = blockIdx.x, dh = blockIdx.y;
    const int b = bch >> 6, ch = bch & 63;
    const size_t vbase = ((size_t)b * LL + ch * 32) * DD + dh * 256;

    // stage PPT via async direct-to-LDS (already transposed+swizzled in global)
    {
        const ushort_t* ppg = PPg + ((size_t)bch * 512 + dh * 256) * 64;
        #pragma unroll
        for (int i = 0; i < 8; ++i)
            gl_lds16(ppg + (size_t)(i * 256 + t) * 8,
                     (char*)PPT + (size_t)(i * 256 + t) * 16);
    }
    // stage V^T
    {
        const int lg = t >> 5, dg = t & 31;
        ushort8 r[4];
        #pragma unroll
        for (int i = 0; i < 4; ++i)
            r[i] = *(const ushort8*)((const ushort_t*)Vb + vbase
                                     + (size_t)(lg * 4 + i) * DD + dg * 8);
        #pragma unroll
        for (int jd = 0; jd < 8; ++jd) {
            ushort4 w4 = {r[0][jd], r[1][jd], r[2][jd], r[3][jd]};
            *(ushort4*)&VT[(dg * 8 + jd) * 40 + lg * 4] = w4;
        }
    }
    // stage CS rows
    {
        const int half = t >> 7;
        const int tt = t & 127;
        const int lrow = tt >> 2, kq = tt & 3;
        const float* srcp = half ? Sa : Ca;
        float4 v0 = *(const float4*)(srcp + ((size_t)b * LL + ch * 32 + lrow) * KK + kq * 8);
        float4 v1 = *(const float4*)(srcp + ((size_t)b * LL + ch * 32 + lrow) * KK + kq * 8 + 4);
        ushort8 w8 = {f2b(v0.x), f2b(v0.y), f2b(v0.z), f2b(v0.w),
                      f2b(v1.x), f2b(v1.y), f2b(v1.z), f2b(v1.w)};
        *(ushort8*)&CS[lrow * 80 + half * 32 + kq * 8] = w8;
    }
    __syncthreads();

    const int w = t >> 6, l = t & 63, l15 = l & 15, hi = l >> 4;

    // G = tri(C@C^T + S@S^T)
    {
        bf16x8 fc[2], fs[2];
        #pragma unroll
        for (int mt = 0; mt < 2; ++mt) {
            fc[mt] = *(const bf16x8*)&CS[(l15 + 16 * mt) * 80 + hi * 8];
            fs[mt] = *(const bf16x8*)&CS[(l15 + 16 * mt) * 80 + 32 + hi * 8];
        }
        f32x4 gacc[2][2];
        #pragma unroll
        for (int mt = 0; mt < 2; ++mt)
            #pragma unroll
            for (int nt = 0; nt < 2; ++nt) {
                gacc[mt][nt] = f32x4{0.f,0.f,0.f,0.f};
                gacc[mt][nt] = __builtin_amdgcn_mfma_f32_16x16x32_bf16(fc[mt], fc[nt], gacc[mt][nt], 0,0,0);
                gacc[mt][nt] = __builtin_amdgcn_mfma_f32_16x16x32_bf16(fs[mt], fs[nt], gacc[mt][nt], 0,0,0);
            }
        #pragma unroll
        for (int mt = 0; mt < 2; ++mt)
            #pragma unroll
            for (int nt = 0; nt < 2; ++nt)
                #pragma unroll
                for (int r = 0; r < 4; ++r) {
                    const int row = 16 * mt + hi * 4 + r;
                    const int col = 16 * nt + l15;
                    float gv = (col <= row) ? gacc[mt][nt][r] : 0.f;
                    G[row * 40 + col] = f2b(gv);
                }
    }

    // main accumulation
    bf16x8 a1[2][2], ag[2];
    #pragma unroll
    for (int mt = 0; mt < 2; ++mt) {
        a1[mt][0] = *(const bf16x8*)&CS[(l15 + 16 * mt) * 80 + hi * 8];
        a1[mt][1] = *(const bf16x8*)&CS[(l15 + 16 * mt) * 80 + 32 + hi * 8];
        ag[mt]    = *(const bf16x8*)&G[(l15 + 16 * mt) * 40 + hi * 8];
    }
    f32x4 acc[2][4];
    #pragma unroll
    for (int mt = 0; mt < 2; ++mt)
        #pragma unroll
        for (int nt = 0; nt < 4; ++nt)
            acc[mt][nt] = f32x4{0.f,0.f,0.f,0.f};
    #pragma unroll
    for (int nt = 0; nt < 4; ++nt) {
        const int drow = w * 64 + nt * 16 + l15;
        bf16x8 bp0 = *(const bf16x8*)((const char*)PPT + drow * 128 + ((hi ^ (drow & 7)) << 4));
        bf16x8 bp1 = *(const bf16x8*)((const char*)PPT + drow * 128 + (((4 + hi) ^ (drow & 7)) << 4));
        bf16x8 bv  = *(const bf16x8*)&VT[drow * 40 + hi * 8];
        #pragma unroll
        for (int mt = 0; mt < 2; ++mt) {
            acc[mt][nt] = __builtin_amdgcn_mfma_f32_16x16x32_bf16(a1[mt][0], bp0, acc[mt][nt], 0,0,0);
            acc[mt][nt] = __builtin_amdgcn_mfma_f32_16x16x32_bf16(a1[mt][1], bp1, acc[mt][nt], 0,0,0);
            acc[mt][nt] = __builtin_amdgcn_mfma_f32_16x16x32_bf16(ag[mt],    bv,  acc[mt][nt], 0,0,0);
        }
    }

    // epilogue: scale + stats accumulate + RT slab
    float sP[2][4] = {}, qP[2][4] = {};
    #pragma unroll
    for (int mt = 0; mt < 2; ++mt)
        #pragma unroll
        for (int nt = 0; nt < 4; ++nt)
            #pragma unroll
            for (int r = 0; r < 4; ++r) {
                const int lrow = 16 * mt + hi * 4 + r;
                const float scale = rsqrtf((float)((ch * 32 + lrow + 1) * KK));
                const float val = acc[mt][nt][r] * scale;
                sP[mt][r] += val;
                qP[mt][r] = fmaf(val, val, qP[mt][r]);
                RT[w][lrow * 64 + nt * 16 + l15] = f2b(val);
            }
    // coalesced in-place store (wave-local)
    #pragma unroll
    for (int c = 0; c < 4; ++c) {
        const int cid = c * 64 + l;
        const int row = cid >> 3, c8 = cid & 7;
        ushort8 v = *(const ushort8*)&RT[w][row * 64 + c8 * 8];
        *(ushort8*)((ushort_t*)Vb + ((size_t)b * LL + ch * 32 + row) * DD
                    + dh * 256 + w * 64 + c8 * 8) = v;
    }
    // stats: reduce over the 16-lane (l15) group, combine waves via LDS
    #pragma unroll
    for (int mt = 0; mt < 2; ++mt)
        #pragma unroll
        for (int r = 0; r < 4; ++r) {
            float sv = sP[mt][r], qv = qP[mt][r];
            #pragma unroll
            for (int off = 1; off < 16; off <<= 1) {
                sv += __shfl_xor(sv, off);
                qv += __shfl_xor(qv, off);
            }
            if (l15 == 0)
                statsL[w][16 * mt + hi * 4 + r] = float2{sv, qv};
        }
    __syncthreads();
    if (t < 32) {
        float s = 0.f, q = 0.f;
        #pragma unroll
        for (int w4 = 0; w4 < 4; ++w4) {
            float2 p = statsL[w4][t];
            s += p.x; q += p.y;
        }
        const size_t rowg = (size_t)b * LL + ch * 32 + t;
        *(float2*)&StatsG[(rowg * 2 + dh) * 2] = float2{s, q};
    }
}

// ---------------------------------------------------------------------------
extern "C" void kernel_launch(void* const* d_in, const int* in_sizes, int n_in,
                              void* d_out, int out_size, void* d_ws, size_t ws_size,
                              hipStream_t stream)
{
    const float* x   = (const float*)d_in[0];
    const float* W1  = (const float*)d_in[1];
    const float* b1  = (const float*)d_in[2];
    const float* W2  = (const float*)d_in[3];
    const float* b2  = (const float*)d_in[4];
    const float* ps  = (const float*)d_in[5];
    const float* cs  = (const float*)d_in[6];
    const float* Wv  = (const float*)d_in[7];
    const float* bv  = (const float*)d_in[8];
    const float* lng = (const float*)d_in[9];
    const float* lnb = (const float*)d_in[10];
    const float* Wo  = (const float*)d_in[11];
    const float* bo  = (const float*)d_in[12];
    float* out = (float*)d_out;

    char* wsb = (char*)d_ws;
    __hip_bfloat16* Vb  = (__hip_bfloat16*)(wsb);                     // 4 MB
    ushort_t* PPg = (ushort_t*)(wsb + (4u << 20));                    // 8 MB
    float* Ca  = (float*)(wsb + (12u << 20));                         // 512 KB
    float* Sa  = (float*)(wsb + (12u << 20) + (512u << 10));          // 512 KB
    __hip_bfloat16* xb  = (__hip_bfloat16*)(wsb + (13u << 20));       // 4 MB
    __hip_bfloat16* Hb  = (__hip_bfloat16*)(wsb + (17u << 20));       // 4 MB
    __hip_bfloat16* Wct = (__hip_bfloat16*)(wsb + (21u << 20));       // 1 MB
    __hip_bfloat16* Wot = (__hip_bfloat16*)(wsb + (22u << 20));       // 0.5 MB
    float* StatsG = (float*)(wsb + (23u << 20));                      // 64 KB
    float* U      = (float*)(wsb + (23u << 20) + (64u << 10));        // 2 KB
    float* VBc    = (float*)(wsb + (23u << 20) + (66u << 10));        // 2 KB

    hipMemsetAsync(U, 0, 4096, stream);   // zero U + VBc (contiguous)
    prep<<<dim3(16, 16, 5), dim3(32, 8), 0, stream>>>(
        W1, Wv, Wo, x, lng, lnb, bo, Wct, Wot, xb, U, VBc);
    gemm_mfma<128, 0><<<dim3(8, 32), dim3(256), 0, stream>>>(
        (const ushort_t*)xb, (const ushort_t*)Wct, b1, bv, nullptr, Hb, Vb, nullptr, nullptr);
    phase_kernel<<<dim3(BL / 8), dim3(256), 0, stream>>>(Hb, W2, b2, ps, cs, Ca, Sa);
    scanA<<<dim3(BB * NCH, 2), dim3(256), 0, stream>>>(Vb, Ca, Sa, PPg);
    scan_prefix<<<dim3(128), dim3(256), 0, stream>>>(PPg);
    scanC<<<dim3(BB * NCH, 2), dim3(256), 0, stream>>>(Vb, Ca, Sa, PPg, StatsG);
    gemm_mfma<64, 1><<<dim3(4, 64), dim3(256), 0, stream>>>(
        (const ushort_t*)Vb, (const ushort_t*)Wot, U, VBc, x, nullptr, nullptr, out, StatsG);
}